// Round 1
// baseline (297.093 us; speedup 1.0000x reference)
//
#include <hip/hip_runtime.h>

// CustomRNN: B=2048 batches, T=512 steps, I=1, H=64.
// Mapping: one wave per batch; lane j owns h[j] and W_hh row j in registers
// (16 float4). Hidden state h lives in LDS (one 64-float buffer per wave);
// all lanes read it with broadcast (same-address) ds_read_b128 — conflict-free.
// Single-wave ownership of the LDS buffer => no __syncthreads needed; DS ops
// from one wave execute in order, wave_barrier() just pins compiler ordering.

#define WPB 4  // waves (== batches) per block

__global__ __launch_bounds__(WPB * 64, 2) void rnn_fused(
    const float* __restrict__ x,      // [B, T, 1]
    const float* __restrict__ W_ih,   // [64, 1]
    const float* __restrict__ W_hh,   // [64, 64]
    const float* __restrict__ b_ih,   // [64]
    const float* __restrict__ b_hh,   // [64]
    const float* __restrict__ fc_w,   // [1, 64]
    const float* __restrict__ fc_b,   // [1]
    float* __restrict__ out,          // [B, 1]
    int B, int T)
{
    const int lane  = threadIdx.x & 63;
    const int wv    = threadIdx.x >> 6;
    const int batch = blockIdx.x * WPB + wv;
    if (batch >= B) return;  // no block-level sync anywhere, early-exit is safe

    __shared__ __align__(16) float hs[WPB][64];
    __shared__ float xs[WPB][64];

    // Lane j caches W_hh row j (the weights feeding output element j).
    float4 w[16];
    {
        const float4* wrow = (const float4*)(W_hh + lane * 64);
#pragma unroll
        for (int i = 0; i < 16; ++i) w[i] = wrow[i];
    }
    const float wih_j  = W_ih[lane];
    const float bias_j = b_ih[lane] + b_hh[lane];

    const float* xb = x + (size_t)batch * T;

    hs[wv][lane] = 0.0f;
    __builtin_amdgcn_wave_barrier();

    float hcur = 0.0f;  // this lane's h[j], mirrored in hs[wv][lane]

    for (int t0 = 0; t0 < T; t0 += 64) {
        // Stage the next 64 input scalars for this batch (coalesced 256B load).
        xs[wv][lane] = (t0 + lane < T) ? xb[t0 + lane] : 0.0f;
        __builtin_amdgcn_wave_barrier();

        const int tend = (T - t0 < 64) ? (T - t0) : 64;
        for (int tt = 0; tt < tend; ++tt) {
            const float xv = xs[wv][tt];  // broadcast read
            const float4* h4 = (const float4*)(&hs[wv][0]);

            // 4 independent FMA chains of length 16 to hide VALU latency.
            float a0 = fmaf(xv, wih_j, bias_j);
            float a1 = 0.0f, a2 = 0.0f, a3 = 0.0f;
#pragma unroll
            for (int k = 0; k < 16; ++k) {
                const float4 hv = h4[k];  // broadcast ds_read_b128
                a0 = fmaf(hv.x, w[k].x, a0);
                a1 = fmaf(hv.y, w[k].y, a1);
                a2 = fmaf(hv.z, w[k].z, a2);
                a3 = fmaf(hv.w, w[k].w, a3);
            }
            float a = (a0 + a1) + (a2 + a3);

            // tanh(a) = sign(a) * (1 - e) / (1 + e),  e = exp(-2|a|) in (0,1]
            const float ax = fabsf(a);
            const float e  = __expf(-2.0f * ax);
            const float th = (1.0f - e) / (1.0f + e);
            hcur = copysignf(th, a);

            __builtin_amdgcn_wave_barrier();   // all reads of this step done
            hs[wv][lane] = hcur;
            __builtin_amdgcn_wave_barrier();   // write ordered before next reads
        }
    }

    // fc: out[b] = sum_j h[j] * fc_w[j] + fc_b
    float v = hcur * fc_w[lane];
#pragma unroll
    for (int off = 32; off > 0; off >>= 1)
        v += __shfl_xor(v, off, 64);
    if (lane == 0) out[batch] = v + fc_b[0];
}

extern "C" void kernel_launch(void* const* d_in, const int* in_sizes, int n_in,
                              void* d_out, int out_size, void* d_ws, size_t ws_size,
                              hipStream_t stream) {
    const float* x    = (const float*)d_in[0];
    const float* W_ih = (const float*)d_in[1];
    const float* W_hh = (const float*)d_in[2];
    const float* b_ih = (const float*)d_in[3];
    const float* b_hh = (const float*)d_in[4];
    const float* fc_w = (const float*)d_in[5];
    const float* fc_b = (const float*)d_in[6];
    float* out = (float*)d_out;

    const int B = out_size;            // output is [B, 1]
    const int T = in_sizes[0] / B;     // I == 1, so x has B*T elements

    const int blocks = (B + WPB - 1) / WPB;
    rnn_fused<<<blocks, WPB * 64, 0, stream>>>(x, W_ih, W_hh, b_ih, b_hh,
                                               fc_w, fc_b, out, B, T);
}

// Round 2
// 210.589 us; speedup vs baseline: 1.4108x; 1.4108x over previous
//
#include <hip/hip_runtime.h>

// CustomRNN: B=2048, T=512, I=1, H=64.
// One wave per batch; lane j owns h[j] and W_hh row j in registers (32 x
// float2 = 64 VGPRs). h broadcast via LDS (16 ds_read_b128, same-address
// broadcast = conflict-free). Dot product uses v_pk_fma_f32 (float2
// ext-vectors) in 4 independent chains. amdgpu_waves_per_eu(2,2) pins the
// register budget to 256 VGPRs so the weight cache provably stays resident
// (round 1: allocator targeted ~8 waves/EU -> 52 VGPRs -> weights were
// rematerialized in the hot loop).

typedef float v2f __attribute__((ext_vector_type(2)));
typedef float v4f __attribute__((ext_vector_type(4)));

#define WPB 4  // waves (== batches) per block

__global__ __launch_bounds__(WPB * 64)
__attribute__((amdgpu_waves_per_eu(2, 2)))
void rnn_fused(
    const float* __restrict__ x,      // [B, T, 1]
    const float* __restrict__ W_ih,   // [64, 1]
    const float* __restrict__ W_hh,   // [64, 64]
    const float* __restrict__ b_ih,   // [64]
    const float* __restrict__ b_hh,   // [64]
    const float* __restrict__ fc_w,   // [1, 64]
    const float* __restrict__ fc_b,   // [1]
    float* __restrict__ out,          // [B, 1]
    int B, int T)
{
    const int lane  = threadIdx.x & 63;
    const int wv    = threadIdx.x >> 6;
    const int batch = blockIdx.x * WPB + wv;
    if (batch >= B) return;  // no block-wide sync anywhere; early exit safe

    __shared__ __align__(16) float hs[WPB][64];
    __shared__ __align__(16) float xs[WPB][64];

    // Lane j caches W_hh row j as 32 float2 (64 VGPRs).
    v2f w[32];
    {
        const v2f* wrow = (const v2f*)(W_hh + lane * 64);
#pragma unroll
        for (int i = 0; i < 32; ++i) w[i] = wrow[i];
    }
    const float wih_j  = W_ih[lane];
    const float bias_j = b_ih[lane] + b_hh[lane];

    const float* xb = x + (size_t)batch * T;

    hs[wv][lane] = 0.0f;
    __builtin_amdgcn_wave_barrier();

    float hcur = 0.0f;  // this lane's h[j], mirrored in hs[wv][lane]

    // One RNN step: a = x*W_ih + bias + W_hh[j,:] . h ; h = tanh(a)
    auto step = [&](float xv) {
        const v4f* h4 = (const v4f*)(&hs[wv][0]);
        v2f a0 = {__builtin_fmaf(xv, wih_j, bias_j), 0.0f};
        v2f a1 = {0.0f, 0.0f}, a2 = {0.0f, 0.0f}, a3 = {0.0f, 0.0f};
#pragma unroll
        for (int k = 0; k < 16; ++k) {
            const v4f hv  = h4[k];  // broadcast ds_read_b128
            const v2f hlo = __builtin_shufflevector(hv, hv, 0, 1);
            const v2f hhi = __builtin_shufflevector(hv, hv, 2, 3);
            if (k & 1) {
                a2 = __builtin_elementwise_fma(hlo, w[2 * k],     a2);
                a3 = __builtin_elementwise_fma(hhi, w[2 * k + 1], a3);
            } else {
                a0 = __builtin_elementwise_fma(hlo, w[2 * k],     a0);
                a1 = __builtin_elementwise_fma(hhi, w[2 * k + 1], a1);
            }
        }
        const v2f s01 = (a0 + a1) + (a2 + a3);  // v_pk_add_f32
        const float a = s01.x + s01.y;

        // tanh(a) = sign(a) * (1 - e) / (1 + e),  e = exp(-2|a|)
        const float ax = __builtin_fabsf(a);
        const float e  = __builtin_amdgcn_exp2f(ax * -2.885390082f); // exp(-2ax)
        const float r  = __builtin_amdgcn_rcpf(1.0f + e);
        const float th = (1.0f - e) * r;
        hcur = __builtin_copysignf(th, a);

        __builtin_amdgcn_wave_barrier();   // all reads of this step done
        hs[wv][lane] = hcur;
        __builtin_amdgcn_wave_barrier();   // write ordered before next reads
    };

    for (int t0 = 0; t0 < T; t0 += 64) {
        const int rem = T - t0;
        // Stage up to 64 input scalars for this batch (coalesced 256B load).
        xs[wv][lane] = (lane < rem) ? xb[t0 + lane] : 0.0f;
        __builtin_amdgcn_wave_barrier();

        if (rem >= 64) {
            const v4f* xs4 = (const v4f*)(&xs[wv][0]);
            for (int t4 = 0; t4 < 16; ++t4) {
                const v4f xq = xs4[t4];  // one broadcast b128 per 4 steps
                step(xq.x);
                step(xq.y);
                step(xq.z);
                step(xq.w);
            }
        } else {
            for (int tt = 0; tt < rem; ++tt) step(xs[wv][tt]);
        }
    }

    // fc: out[b] = sum_j h[j] * fc_w[j] + fc_b
    float v = hcur * fc_w[lane];
#pragma unroll
    for (int off = 32; off > 0; off >>= 1)
        v += __shfl_xor(v, off, 64);
    if (lane == 0) out[batch] = v + fc_b[0];
}

extern "C" void kernel_launch(void* const* d_in, const int* in_sizes, int n_in,
                              void* d_out, int out_size, void* d_ws, size_t ws_size,
                              hipStream_t stream) {
    const float* x    = (const float*)d_in[0];
    const float* W_ih = (const float*)d_in[1];
    const float* W_hh = (const float*)d_in[2];
    const float* b_ih = (const float*)d_in[3];
    const float* b_hh = (const float*)d_in[4];
    const float* fc_w = (const float*)d_in[5];
    const float* fc_b = (const float*)d_in[6];
    float* out = (float*)d_out;

    const int B = out_size;          // output is [B, 1]
    const int T = in_sizes[0] / B;   // I == 1, so x has B*T elements

    const int blocks = (B + WPB - 1) / WPB;
    rnn_fused<<<blocks, WPB * 64, 0, stream>>>(x, W_ih, W_hh, b_ih, b_hh,
                                               fc_w, fc_b, out, B, T);
}